// Round 4
// baseline (2517.998 us; speedup 1.0000x reference)
//
#include <hip/hip_runtime.h>

#define NB 512
#define NT 256
#define NI 32
#define NH 128
#define NG 512
#define TC 32
#define NCH 8            // NT/TC
#define NBLK 256         // total blocks: 32 role0 + 32 role1 + 192 gemm workers
#define NWB 152          // gemmB workers (h0 -> xg1, K=128)
#define NWA 40           // gemmA workers (x -> xg0,  K=32)

#define L2E  1.4426950408889634f
#define L2E2 2.8853900817779268f

typedef __attribute__((ext_vector_type(8))) short bf16x8;
typedef __attribute__((ext_vector_type(4))) float f32x4;

constexpr size_t XGCH = (size_t)NB * TC * NG;   // floats per xg chunk (8M)
constexpr size_t H0CH = (size_t)NB * TC * NH;   // floats per h0 chunk (2M)

__device__ __forceinline__ unsigned short f2bf_rne(float f) {
    unsigned u = __float_as_uint(f);
    return (unsigned short)((u + 0x7FFFu + ((u >> 16) & 1u)) >> 16);
}
__device__ __forceinline__ void split2(float a, float b, unsigned& hi, unsigned& lo) {
    unsigned short ha = f2bf_rne(a), hb = f2bf_rne(b);
    float ra = a - __uint_as_float((unsigned)ha << 16);
    float rb = b - __uint_as_float((unsigned)hb << 16);
    hi = (unsigned)ha | ((unsigned)hb << 16);
    lo = (unsigned)f2bf_rne(ra) | ((unsigned)f2bf_rne(rb) << 16);
}
__device__ __forceinline__ bf16x8 u4bf(uint4 u) {
    union { uint4 u; bf16x8 v; } c; c.u = u; return c.v;
}
#define MFMA16(accv, av, bv) \
    accv = __builtin_amdgcn_mfma_f32_16x16x32_bf16(av, bv, accv, 0, 0, 0)

// LDS-only barrier: orders ds ops across waves WITHOUT draining vmcnt.
__device__ __forceinline__ void lds_barrier() {
    asm volatile("s_waitcnt lgkmcnt(0)\n\ts_barrier" ::: "memory");
}

// Device-scope grid barrier: one counter per sync point (memset to 0 by host
// each launch). __threadfence (agent fence) on both sides handles the
// per-XCD-L2 non-coherence (wbl2 on release path / inv on acquire path).
__device__ __forceinline__ void gsync(unsigned* ctr) {
    __threadfence();
    __syncthreads();
    if (threadIdx.x == 0) {
        __hip_atomic_fetch_add(ctr, 1u, __ATOMIC_ACQ_REL, __HIP_MEMORY_SCOPE_AGENT);
        while (__hip_atomic_load(ctr, __ATOMIC_ACQUIRE, __HIP_MEMORY_SCOPE_AGENT)
               < (unsigned)NBLK)
            __builtin_amdgcn_s_sleep(1);
    }
    __syncthreads();
    __threadfence();
}

// ---------------------------------------------------------------------------
// Persistent cooperative mega-kernel (R18).
//   blocks  0-31 : layer-0 recurrence, batch-group p, chunk i    (reads xg0)
//   blocks 32-63 : layer-1 recurrence, batch-group p, chunk i-2  (reads xg1)
//   blocks 64-255: GEMM workers: xg1(i-1) = -(h0(i-1).W_ih1^T+b)*s   [K=128]
//                                 xg0(i+1) = -(x_chunk.W_ih0^T+b)*s  [K=32]
// Iterations i = -1 .. NCH+1, device barrier between iterations. All chunk
// buffers parity-double-buffered; every read is of a buffer completed in a
// PREVIOUS iteration, so there are no intra-iteration cross-block deps.
// Weights (wh/wl split-bf16, log2e-prescaled) persist in registers; h/c
// state persists in LDS/registers across all 256 steps; fixed per-dispatch
// cost (~30us x 8, measured R16 vs R17 marginal fit) is paid once.
// ---------------------------------------------------------------------------
__global__ __launch_bounds__(512, 1)
void mega(const float* __restrict__ x,
          const float* __restrict__ w_hh0, const float* __restrict__ w_hh1,
          const float* __restrict__ w_ih0, const float* __restrict__ b_ih0,
          const float* __restrict__ b_hh0,
          const float* __restrict__ w_ih1, const float* __restrict__ b_ih1,
          const float* __restrict__ b_hh1,
          const float* __restrict__ fc1w, const float* __restrict__ fc1b,
          const float* __restrict__ fc2w, const float* __restrict__ fc2b,
          float* __restrict__ xg0, float* __restrict__ xg1,
          float* __restrict__ h0,  float* __restrict__ h1s,
          float* __restrict__ out, unsigned* __restrict__ bar)
{
    __shared__ __align__(16) unsigned short Hh[2][16][128];    // 8 KB (roles)
    __shared__ __align__(16) unsigned short Hl[2][16][128];    // 8 KB
    __shared__ __align__(16) unsigned short GAh[4][128][8], GAl[4][128][8]; // 16 KB (gemm)
    __shared__ __align__(16) unsigned short GBh[4][64][8],  GBl[4][64][8];  //  8 KB

    const int bid  = blockIdx.x;
    const int tid  = threadIdx.x;
    const int wv   = tid >> 6;
    const int lane = tid & 63;
    const int quad = lane >> 4;
    const int ml   = lane & 15;

    if (bid < 64) {
        // =================== recurrence roles ===================
        const int role = bid >> 5;
        const int p    = bid & 31;
        const int j    = 16 * wv + ml;
        const float* wsrc = role ? w_hh1 : w_hh0;

        // ---- stage W_hh (log2e-prescaled) hi+lo in registers, once ----
        bf16x8 wh[4][4], wl[4][4];
#pragma unroll
        for (int t = 0; t < 4; ++t) {
            const float sc = (t == 2) ? L2E2 : L2E;
#pragma unroll
            for (int q = 0; q < 4; ++q) {
                int n = (t * 8 + wv) * 16 + ml;
                const float* s = wsrc + (size_t)n * NH + q * 32 + quad * 8;
                float4 v0 = *(const float4*)s;
                float4 v1 = *(const float4*)(s + 4);
                uint4 H, L;
                split2(v0.x * sc, v0.y * sc, H.x, L.x); split2(v0.z * sc, v0.w * sc, H.y, L.y);
                split2(v1.x * sc, v1.y * sc, H.z, L.z); split2(v1.z * sc, v1.w * sc, H.w, L.w);
                wh[t][q] = u4bf(H);
                wl[t][q] = u4bf(L);
            }
        }

        // ---- per-thread offsets ----
        int ro[4];
#pragma unroll
        for (int q = 0; q < 4; ++q)
            ro[q] = ((ml * 256 + q * 64 + quad * 16) ^ ((ml & 7) << 4));
        int wo[4];
        size_t hb_r[4], sb_r[4];
#pragma unroll
        for (int r = 0; r < 4; ++r) {
            int m = quad * 4 + r;
            wo[r]   = ((m * 256 + j * 2) ^ ((m & 7) << 4));
            hb_r[r] = (size_t)(p * 16 + m) * TC * NH + j;   // chunk-local h0 row
            sb_r[r] = (size_t)(p * 16 + m) * NH + j;        // h1s row
        }

        // ---- init h = 0 (LDS buf 0), c = 0 ----
        float cr[4] = {};
#pragma unroll
        for (int r = 0; r < 4; ++r) {
            *(unsigned short*)((char*)&Hh[0][0][0] + wo[r]) = 0;
            *(unsigned short*)((char*)&Hl[0][0][0] + wo[r]) = 0;
        }
        __syncthreads();

        // fused activation: inputs m_* = -(log2e-scaled preact)
        auto activ = [&](float mi, float mf, float mg, float mo, float& c)
            __attribute__((always_inline)) -> float {
            float ei = exp2f(mi), ef = exp2f(mf), eg = exp2f(mg), eo = exp2f(mo);
            float rf  = __builtin_amdgcn_rcpf(1.0f + ef);
            float rig = __builtin_amdgcn_rcpf((1.0f + ei) * (1.0f + eg));
            float cn  = c * rf + (1.0f - eg) * rig;
            c = cn;
            float ec = exp2f(cn * -L2E2);
            float rh = __builtin_amdgcn_rcpf((1.0f + eo) * (1.0f + ec));
            return (1.0f - ec) * rh;
        };

        const size_t rs    = (size_t)TC * NG;
        const size_t rowb0 = ((size_t)(p * 16 + quad * 4) * TC) * NG + j;

        for (int i = -1; i <= NCH + 1; ++i) {
            const int c = role ? i - 2 : i;      // chunk this role processes
            if (c >= 0 && c < NCH) {
                const float* xg   = (role ? xg1 : xg0) + (size_t)(c & 1) * XGCH;
                float*       hout = role ? nullptr : h0 + (size_t)(c & 1) * H0CH;
                const bool   last = role && (c == NCH - 1);

                auto prefetch = [&](float (&dst)[4][4], int tlx)
                    __attribute__((always_inline)) {
                    int tc_ = tlx < TC ? tlx : TC - 1;   // clamp inside chunk
                    const size_t rowb = rowb0 + (size_t)tc_ * NG;
#pragma unroll
                    for (int t = 0; t < 4; ++t)
#pragma unroll
                        for (int r = 0; r < 4; ++r)
                            dst[t][r] = xg[rowb + (size_t)r * rs + t * 128];
                };

                auto step = [&](int TL, int BUF, const float (&xgv)[4][4])
                    __attribute__((always_inline)) {
                    const char* hb = (const char*)&Hh[BUF][0][0];
                    const char* lb = (const char*)&Hl[BUF][0][0];
                    char* hbn = (char*)&Hh[BUF ^ 1][0][0];
                    char* lbn = (char*)&Hl[BUF ^ 1][0][0];

                    f32x4 P[4] = {}, Q[4] = {};
#pragma unroll
                    for (int q = 0; q < 4; ++q) {
                        bf16x8 ah = *(const bf16x8*)(hb + ro[q]);
                        bf16x8 al = *(const bf16x8*)(lb + ro[q]);
#pragma unroll
                        for (int t = 0; t < 4; ++t) {
                            MFMA16(P[t], ah, wh[t][q]);
                            MFMA16(Q[t], al, wh[t][q]);
                            if (q & 1) { MFMA16(P[t], ah, wl[t][q]); }
                            else       { MFMA16(Q[t], ah, wl[t][q]); }
                        }
                    }
#pragma unroll
                    for (int r = 0; r < 4; ++r) {
                        float mi = xgv[0][r] - P[0][r] - Q[0][r];
                        float mf = xgv[1][r] - P[1][r] - Q[1][r];
                        float mg = xgv[2][r] - P[2][r] - Q[2][r];
                        float mo = xgv[3][r] - P[3][r] - Q[3][r];
                        float hn = activ(mi, mf, mg, mo, cr[r]);
                        unsigned short hi = f2bf_rne(hn);
                        float res = hn - __uint_as_float((unsigned)hi << 16);
                        unsigned short lo = f2bf_rne(res);
                        *(unsigned short*)(hbn + wo[r]) = hi;
                        *(unsigned short*)(lbn + wo[r]) = lo;
                        if (hout)
                            hout[hb_r[r] + (size_t)TL * NH] = hn;
                        if (last && TL == TC - 1)
                            h1s[sb_r[r]] = hn;
                    }
                };

                float xga[4][4], xgb[4][4];
                prefetch(xga, 0);
                for (int tl = 0; tl < TC; tl += 2) {
                    prefetch(xgb, tl + 1);
                    step(tl, 0, xga);
                    lds_barrier();
                    prefetch(xga, tl + 2);
                    step(tl + 1, 1, xgb);
                    lds_barrier();
                }
            }
            gsync(&bar[i + 1]);
        }

        // =================== fc head (role0 blocks) ===================
        if (role == 0) {
            const int g = tid >> 5;          // 0..15 -> batch p*16+g
            const int l = tid & 31;
            const float4* h4 = (const float4*)(h1s + (size_t)(p * 16 + g) * NH);
            const float4* w0 = (const float4*)(fc1w + (size_t)l * NH);
            const float4* w1 = (const float4*)(fc1w + (size_t)(l + 32) * NH);
            float a0 = fc1b[l], a1 = fc1b[l + 32];
#pragma unroll
            for (int q = 0; q < 32; ++q) {
                float4 h = h4[q], u = w0[q], v = w1[q];
                a0 += u.x * h.x + u.y * h.y + u.z * h.z + u.w * h.w;
                a1 += v.x * h.x + v.y * h.y + v.z * h.z + v.w * h.w;
            }
            float pv = fc2w[l] * fmaxf(a0, 0.f) + fc2w[l + 32] * fmaxf(a1, 0.f);
#pragma unroll
            for (int off = 16; off > 0; off >>= 1) pv += __shfl_down(pv, off, 32);
            if (l == 0) out[p * 16 + g] = pv + fc2b[0];
        }
        return;
    }

    // =================== GEMM workers ===================
    const int w = bid - 64;

    // tile gemm: C[row][NG] = -(A.Bw^T + (bi+bh)) * s_gate, split-bf16 MFMA.
    // KP = K/32. SLICED: A = x with rows b*NT + t0 + tl (chunk slice).
    auto gemm_run = [&](const float* __restrict__ A, const float* __restrict__ Bw,
                        const float* __restrict__ bi, const float* __restrict__ bh,
                        float* __restrict__ C, int t0, int wk, int nw,
                        int KP, bool SLICED) __attribute__((always_inline)) {
        const int AS = SLICED ? NI : NH;     // A row stride (= K)
        for (int tile = wk; tile < 1024; tile += nw) {
            const int n0 = (tile & 7) * 64;
            const int m0 = (tile >> 3) * 128;
            const float s = ((n0 >> 7) == 2) ? L2E2 : L2E;
            f32x4 acc[4] = {};
            for (int kp = 0; kp < KP; ++kp) {
                __syncthreads();
                {   // stage A: 512 threads = 128 m x 4 ck
                    int m = tid >> 2, ck = tid & 3;
                    size_t abase;
                    if (SLICED) {
                        int mg = m0 + m;
                        int b  = mg >> 5, tl = mg & 31;     // TC = 32
                        abase = ((size_t)b * NT + (t0 + tl)) * AS;
                    } else {
                        abase = (size_t)(m0 + m) * AS;
                    }
                    const float* sp = A + abase + kp * 32 + ck * 8;
                    float4 v0 = *(const float4*)sp;
                    float4 v1 = *(const float4*)(sp + 4);
                    uint4 H, L;
                    split2(v0.x, v0.y, H.x, L.x); split2(v0.z, v0.w, H.y, L.y);
                    split2(v1.x, v1.y, H.z, L.z); split2(v1.z, v1.w, H.w, L.w);
                    *(uint4*)&GAh[ck][m][0] = H;
                    *(uint4*)&GAl[ck][m][0] = L;
                }
                if (tid < 256) {   // stage B: 64 n x 4 ck
                    int n = tid >> 2, ck = tid & 3;
                    const float* sp = Bw + (size_t)(n0 + n) * AS + kp * 32 + ck * 8;
                    float4 v0 = *(const float4*)sp;
                    float4 v1 = *(const float4*)(sp + 4);
                    uint4 H, L;
                    split2(v0.x, v0.y, H.x, L.x); split2(v0.z, v0.w, H.y, L.y);
                    split2(v1.x, v1.y, H.z, L.z); split2(v1.z, v1.w, H.w, L.w);
                    *(uint4*)&GBh[ck][n][0] = H;
                    *(uint4*)&GBl[ck][n][0] = L;
                }
                __syncthreads();

                bf16x8 ah = *(const bf16x8*)&GAh[quad][wv * 16 + ml][0];
                bf16x8 al = *(const bf16x8*)&GAl[quad][wv * 16 + ml][0];
#pragma unroll
                for (int nt = 0; nt < 4; ++nt) {
                    bf16x8 bhv = *(const bf16x8*)&GBh[quad][nt * 16 + ml][0];
                    bf16x8 blv = *(const bf16x8*)&GBl[quad][nt * 16 + ml][0];
                    MFMA16(acc[nt], ah, bhv);
                    MFMA16(acc[nt], ah, blv);
                    MFMA16(acc[nt], al, bhv);
                }
            }
#pragma unroll
            for (int nt = 0; nt < 4; ++nt) {
                int n = n0 + nt * 16 + ml;
                float nb = -(bi[n] + bh[n]) * s;
#pragma unroll
                for (int reg = 0; reg < 4; ++reg) {
                    int m = m0 + wv * 16 + quad * 4 + reg;
                    C[(size_t)m * NG + n] = fmaf(acc[nt][reg], -s, nb);
                }
            }
        }
    };

    for (int i = -1; i <= NCH + 1; ++i) {
        if (w < NWB) {
            // xg1 for chunk i-1 from h0 chunk i-1 (written by role0 in iter i-1)
            const int c1 = i - 1;
            if (c1 >= 0 && c1 < NCH)
                gemm_run(h0 + (size_t)(c1 & 1) * H0CH, w_ih1, b_ih1, b_hh1,
                         xg1 + (size_t)(c1 & 1) * XGCH, 0, w, NWB, 4, false);
        } else {
            // xg0 for chunk i+1 from x (consumed by role0 in iter i+1)
            const int c2 = i + 1;
            if (c2 < NCH)
                gemm_run(x, w_ih0, b_ih0, b_hh0,
                         xg0 + (size_t)(c2 & 1) * XGCH, c2 * TC, w - NWB, NWA,
                         1, true);
        }
        gsync(&bar[i + 1]);
    }
}

extern "C" void kernel_launch(void* const* d_in, const int* in_sizes, int n_in,
                              void* d_out, int out_size, void* d_ws, size_t ws_size,
                              hipStream_t stream)
{
    const float* x     = (const float*)d_in[0];
    const float* w_ih0 = (const float*)d_in[1];
    const float* w_hh0 = (const float*)d_in[2];
    const float* b_ih0 = (const float*)d_in[3];
    const float* b_hh0 = (const float*)d_in[4];
    const float* w_ih1 = (const float*)d_in[5];
    const float* w_hh1 = (const float*)d_in[6];
    const float* b_ih1 = (const float*)d_in[7];
    const float* b_hh1 = (const float*)d_in[8];
    const float* fc1w  = (const float*)d_in[9];
    const float* fc1b  = (const float*)d_in[10];
    const float* fc2w  = (const float*)d_in[11];
    const float* fc2b  = (const float*)d_in[12];
    float* out = (float*)d_out;
    float* ws  = (float*)d_ws;

    // ws layout (floats): xg0[2] | xg1[2] | h0[2] | h1s | barrier counters
    // total = 2*8M + 2*8M + 2*2M + 64K + 64 = 37,814,336 floats = 151.3 MB
    // (<= proven ws capacity of 152.0 MB from the Tc=64 revisions).
    size_t o_xg0 = 0;
    size_t o_xg1 = o_xg0 + 2 * XGCH;
    size_t o_h0  = o_xg1 + 2 * XGCH;
    size_t o_h1s = o_h0  + 2 * H0CH;
    size_t o_bar = o_h1s + (size_t)NB * NH;

    float* xg0p = ws + o_xg0;
    float* xg1p = ws + o_xg1;
    float* h0p  = ws + o_h0;
    float* h1sp = ws + o_h1s;
    unsigned* barp = (unsigned*)(ws + o_bar);

    hipMemsetAsync(barp, 0, 64 * sizeof(unsigned), stream);

    void* args[] = {
        (void*)&x,
        (void*)&w_hh0, (void*)&w_hh1,
        (void*)&w_ih0, (void*)&b_ih0, (void*)&b_hh0,
        (void*)&w_ih1, (void*)&b_ih1, (void*)&b_hh1,
        (void*)&fc1w, (void*)&fc1b, (void*)&fc2w, (void*)&fc2b,
        (void*)&xg0p, (void*)&xg1p, (void*)&h0p, (void*)&h1sp,
        (void*)&out, (void*)&barp,
    };
    hipLaunchCooperativeKernel((const void*)mega, dim3(NBLK), dim3(512),
                               args, 0, stream);
}

// Round 5
// 739.869 us; speedup vs baseline: 3.4033x; 3.4033x over previous
//
#include <hip/hip_runtime.h>

#define NB 512
#define NT 256
#define NI 32
#define NH 128
#define NG 512
#define WIN 4            // steps per xg1 window
#define NWIN 64          // NT/WIN
#define RING 16          // xg1 ring slots (windows)
#define NWRK 192         // gemm worker blocks

#define L2E  1.4426950408889634f
#define L2E2 2.8853900817779268f

typedef __attribute__((ext_vector_type(8))) short bf16x8;
typedef __attribute__((ext_vector_type(4))) float f32x4;

__device__ __forceinline__ unsigned short f2bf_rne(float f) {
    unsigned u = __float_as_uint(f);
    return (unsigned short)((u + 0x7FFFu + ((u >> 16) & 1u)) >> 16);
}
__device__ __forceinline__ void split2(float a, float b, unsigned& hi, unsigned& lo) {
    unsigned short ha = f2bf_rne(a), hb = f2bf_rne(b);
    float ra = a - __uint_as_float((unsigned)ha << 16);
    float rb = b - __uint_as_float((unsigned)hb << 16);
    hi = (unsigned)ha | ((unsigned)hb << 16);
    lo = (unsigned)f2bf_rne(ra) | ((unsigned)f2bf_rne(rb) << 16);
}
__device__ __forceinline__ bf16x8 u4bf(uint4 u) {
    union { uint4 u; bf16x8 v; } c; c.u = u; return c.v;
}
#define MFMA16(accv, av, bv) \
    accv = __builtin_amdgcn_mfma_f32_16x16x32_bf16(av, bv, accv, 0, 0, 0)

__device__ __forceinline__ void lds_barrier() {
    asm volatile("s_waitcnt lgkmcnt(0)\n\ts_barrier" ::: "memory");
}
__device__ __forceinline__ void vm_drain() {
    asm volatile("s_waitcnt vmcnt(0)" ::: "memory");
}

// ---- AGENT-scope relaxed atomics: every access hits the coherence point
// (LLC) individually -> cross-XCD safe with NO fences / NO L2 writebacks.
__device__ __forceinline__ unsigned long long ald64(const unsigned long long* p) {
    return __hip_atomic_load(p, __ATOMIC_RELAXED, __HIP_MEMORY_SCOPE_AGENT);
}
__device__ __forceinline__ void ast64(unsigned long long* p, unsigned long long v) {
    __hip_atomic_store(p, v, __ATOMIC_RELAXED, __HIP_MEMORY_SCOPE_AGENT);
}
__device__ __forceinline__ unsigned aldu(const unsigned* p) {
    return __hip_atomic_load(p, __ATOMIC_RELAXED, __HIP_MEMORY_SCOPE_AGENT);
}
__device__ __forceinline__ void astu(unsigned* p, unsigned v) {
    __hip_atomic_store(p, v, __ATOMIC_RELAXED, __HIP_MEMORY_SCOPE_AGENT);
}

// fused activation: inputs m_* = -(log2e-scaled preact); updates c, returns h
__device__ __forceinline__ float activ(float mi, float mf, float mg, float mo,
                                       float& c) {
    float ei = exp2f(mi), ef = exp2f(mf), eg = exp2f(mg), eo = exp2f(mo);
    float rf  = __builtin_amdgcn_rcpf(1.0f + ef);
    float rig = __builtin_amdgcn_rcpf((1.0f + ei) * (1.0f + eg));
    float cn  = c * rf + (1.0f - eg) * rig;
    c = cn;
    float ec = exp2f(cn * -L2E2);
    float rh = __builtin_amdgcn_rcpf((1.0f + eo) * (1.0f + ec));
    return (1.0f - ec) * rh;
}

// ---------------------------------------------------------------------------
// R19: single persistent kernel, pairwise LLC message passing (no fences).
//  blocks  0-31 (role0): layer-0 recurrence, x.W_ih0 fused; exports h as
//    split-bf16 planes via b64 AGENT stores; ctr0[p] += 4-step bumps.
//  blocks 64-255 (workers): xg1 windows (WIN steps) per (p,w) tile:
//    A = h0 planes (atomic b64), B = W_ih1 (normal cached loads, read-only),
//    C -> fp32 ring (atomic b64), flagW[p][w] after vmcnt drain.
//  blocks 32-63 (role1): layer-1 recurrence reading the xg ring (atomic b64,
//    prefetched); ctr1[p] = consumed windows (ring backpressure); fc fused.
// Dependency chain role0 -> worker -> role1 is acyclic per p: deadlock-free.
// ---------------------------------------------------------------------------
__global__ __launch_bounds__(512, 1)
void fused(const float* __restrict__ x,
           const float* __restrict__ w_hh0, const float* __restrict__ w_hh1,
           const float* __restrict__ w_ih0, const float* __restrict__ b_ih0,
           const float* __restrict__ b_hh0,
           const float* __restrict__ w_ih1, const float* __restrict__ b_ih1,
           const float* __restrict__ b_hh1,
           const float* __restrict__ fc1w, const float* __restrict__ fc1b,
           const float* __restrict__ fc2w, const float* __restrict__ fc2b,
           unsigned long long* __restrict__ h0pl,  // [256][2][32][512] u64
           float* __restrict__ xgr,                // [RING][32][WIN][512][16]
           float* __restrict__ h1s, float* __restrict__ out,
           unsigned* __restrict__ ctr0, unsigned* __restrict__ flagW,
           unsigned* __restrict__ ctr1)
{
    __shared__ __align__(16) unsigned short HA[2][16][128];   // 8 KB
    __shared__ __align__(16) unsigned short HL[2][16][128];   // 8 KB

    const int bid  = blockIdx.x;
    const int tid  = threadIdx.x;
    const int wv   = tid >> 6;
    const int lane = tid & 63;
    const int quad = lane >> 4;
    const int ml   = lane & 15;

    // =====================================================================
    if (bid >= 64) {                       // ---------------- GEMM workers
        const int wk = bid - 64;
        for (int tile = wk; tile < 32 * NWIN; tile += NWRK) {
            const int w  = tile >> 5;
            const int pp = tile & 31;
            while (aldu(&ctr0[pp * 16]) < (unsigned)(4 * w + 4))
                __builtin_amdgcn_s_sleep(8);
            if (w >= RING)
                while (aldu(&ctr1[pp * 16]) < (unsigned)(w - (RING - 1)))
                    __builtin_amdgcn_s_sleep(8);
            asm volatile("" ::: "memory");

            bf16x8 A[4][4][2];             // [tt][q][plane]
#pragma unroll
            for (int tt = 0; tt < 4; ++tt)
#pragma unroll
                for (int q = 0; q < 4; ++q)
#pragma unroll
                    for (int pl = 0; pl < 2; ++pl) {
                        const unsigned long long* ap =
                            h0pl + (((size_t)(4 * w + tt) * 2 + pl) * 32 + pp) * 512
                                 + ml * 32 + q * 8 + quad * 2;
                        unsigned long long a0 = ald64(ap), a1 = ald64(ap + 1);
                        uint4 U;
                        U.x = (unsigned)a0; U.y = (unsigned)(a0 >> 32);
                        U.z = (unsigned)a1; U.w = (unsigned)(a1 >> 32);
                        A[tt][q][pl] = u4bf(U);
                    }

            f32x4 acc[4][4] = {};
#pragma unroll
            for (int nt = 0; nt < 4; ++nt) {
                const float* bw = w_ih1
                    + (size_t)(wv * 64 + nt * 16 + ml) * NH + quad * 8;
                bf16x8 bh[4], bl[4];
#pragma unroll
                for (int q = 0; q < 4; ++q) {
                    float4 v0 = *(const float4*)(bw + q * 32);
                    float4 v1 = *(const float4*)(bw + q * 32 + 4);
                    uint4 H, L;
                    split2(v0.x, v0.y, H.x, L.x); split2(v0.z, v0.w, H.y, L.y);
                    split2(v1.x, v1.y, H.z, L.z); split2(v1.z, v1.w, H.w, L.w);
                    bh[q] = u4bf(H); bl[q] = u4bf(L);
                }
#pragma unroll
                for (int tt = 0; tt < 4; ++tt)
#pragma unroll
                    for (int q = 0; q < 4; ++q) {
                        MFMA16(acc[tt][nt], A[tt][q][0], bh[q]);
                        MFMA16(acc[tt][nt], A[tt][q][1], bh[q]);
                        MFMA16(acc[tt][nt], A[tt][q][0], bl[q]);
                    }
            }

            const int slot = w & (RING - 1);
            float* cb = xgr + ((size_t)slot * 32 + pp) * WIN * 8192;
#pragma unroll
            for (int nt = 0; nt < 4; ++nt) {
                int n = wv * 64 + nt * 16 + ml;
                float s = ((n >> 7) == 2) ? L2E2 : L2E;
                float nbs = -(b_ih1[n] + b_hh1[n]) * s;
#pragma unroll
                for (int tt = 0; tt < 4; ++tt) {
                    float* cp = cb + (size_t)tt * 8192 + n * 16 + quad * 4;
                    float v0 = fmaf(acc[tt][nt][0], -s, nbs);
                    float v1 = fmaf(acc[tt][nt][1], -s, nbs);
                    float v2 = fmaf(acc[tt][nt][2], -s, nbs);
                    float v3 = fmaf(acc[tt][nt][3], -s, nbs);
                    ast64((unsigned long long*)cp,
                          (unsigned long long)__float_as_uint(v0) |
                          ((unsigned long long)__float_as_uint(v1) << 32));
                    ast64((unsigned long long*)(cp + 2),
                          (unsigned long long)__float_as_uint(v2) |
                          ((unsigned long long)__float_as_uint(v3) << 32));
                }
            }
            vm_drain();
            __syncthreads();
            if (tid == 0) astu(&flagW[pp * 64 + w], 1u);
        }
        return;
    }

    // =====================================================================
    // recurrence roles
    const int role = bid >> 5;
    const int p    = bid & 31;
    const int j    = 16 * wv + ml;
    const float* wsrc = role ? w_hh1 : w_hh0;

    bf16x8 wh[4][4], wl[4][4];
#pragma unroll
    for (int t = 0; t < 4; ++t) {
        const float sc = (t == 2) ? L2E2 : L2E;
#pragma unroll
        for (int q = 0; q < 4; ++q) {
            int n = (t * 8 + wv) * 16 + ml;
            const float* s = wsrc + (size_t)n * NH + q * 32 + quad * 8;
            float4 v0 = *(const float4*)s;
            float4 v1 = *(const float4*)(s + 4);
            uint4 H, L;
            split2(v0.x * sc, v0.y * sc, H.x, L.x); split2(v0.z * sc, v0.w * sc, H.y, L.y);
            split2(v1.x * sc, v1.y * sc, H.z, L.z); split2(v1.z * sc, v1.w * sc, H.w, L.w);
            wh[t][q] = u4bf(H);
            wl[t][q] = u4bf(L);
        }
    }

    int ro[4];
#pragma unroll
    for (int q = 0; q < 4; ++q)
        ro[q] = ((ml * 256 + q * 64 + quad * 16) ^ ((ml & 7) << 4));
    int wo[4];
#pragma unroll
    for (int r = 0; r < 4; ++r) {
        int m = quad * 4 + r;
        wo[r] = ((m * 256 + j * 2) ^ ((m & 7) << 4));
    }

    float cr[4] = {};
#pragma unroll
    for (int r = 0; r < 4; ++r) {
        *(unsigned short*)((char*)&HA[0][0][0] + wo[r]) = 0;
        *(unsigned short*)((char*)&HL[0][0][0] + wo[r]) = 0;
    }
    __syncthreads();

    if (role == 0) {
        // ================= role0: layer0, fused x-GEMM, h0 export ========
        bf16x8 wi_h[4], wi_l[4];
        float nb[4];
#pragma unroll
        for (int t = 0; t < 4; ++t) {
            const float sc = (t == 2) ? L2E2 : L2E;
            int n = (t * 8 + wv) * 16 + ml;
            const float* s = w_ih0 + (size_t)n * NI + quad * 8;
            float4 v0 = *(const float4*)s;
            float4 v1 = *(const float4*)(s + 4);
            uint4 H, L;
            split2(v0.x * sc, v0.y * sc, H.x, L.x); split2(v0.z * sc, v0.w * sc, H.y, L.y);
            split2(v1.x * sc, v1.y * sc, H.z, L.z); split2(v1.z * sc, v1.w * sc, H.w, L.w);
            wi_h[t] = u4bf(H);
            wi_l[t] = u4bf(L);
            int nn = t * 128 + j;
            nb[t] = -(b_ih0[nn] + b_hh0[nn]) * sc;
        }

        // export offset: plane linear u64 idx = tid; LDS src byte (swizzled)
        const int erow = tid >> 5;
        const int eoff = erow * 256 + (((tid & 31) * 8) ^ ((erow & 7) << 4));

        const float* xrow = x + (size_t)(p * 16 + ml) * NT * NI + quad * 8;
        auto xload = [&](float4& a, float4& b, int T) __attribute__((always_inline)) {
            const float* sp = xrow + (size_t)T * NI;
            a = *(const float4*)sp;
            b = *(const float4*)(sp + 4);
        };

        auto exp0 = [&](int T, int BUF) __attribute__((always_inline)) {
            // export h_{T-1} (resident in HA/HL[BUF]) -> linear [m][j] planes
            unsigned long long vh =
                *(const unsigned long long*)((const char*)&HA[BUF][0][0] + eoff);
            unsigned long long vl =
                *(const unsigned long long*)((const char*)&HL[BUF][0][0] + eoff);
            ast64(h0pl + (((size_t)(T - 1) * 2 + 0) * 32 + p) * 512 + tid, vh);
            ast64(h0pl + (((size_t)(T - 1) * 2 + 1) * 32 + p) * 512 + tid, vl);
        };

        auto step0 = [&](int TL, int BUF, float4 x0, float4 x1)
            __attribute__((always_inline)) {
            const char* hb = (const char*)&HA[BUF][0][0];
            const char* lb = (const char*)&HL[BUF][0][0];
            char* hbn = (char*)&HA[BUF ^ 1][0][0];
            char* lbn = (char*)&HL[BUF ^ 1][0][0];
            uint4 XH, XL;
            split2(x0.x, x0.y, XH.x, XL.x); split2(x0.z, x0.w, XH.y, XL.y);
            split2(x1.x, x1.y, XH.z, XL.z); split2(x1.z, x1.w, XH.w, XL.w);
            bf16x8 xh = u4bf(XH), xl = u4bf(XL);
            f32x4 P[4] = {}, Q[4] = {};
#pragma unroll
            for (int t = 0; t < 4; ++t) {
                MFMA16(P[t], xh, wi_h[t]);
                MFMA16(Q[t], xl, wi_h[t]);
                MFMA16(Q[t], xh, wi_l[t]);
            }
#pragma unroll
            for (int q = 0; q < 4; ++q) {
                bf16x8 ah = *(const bf16x8*)(hb + ro[q]);
                bf16x8 al = *(const bf16x8*)(lb + ro[q]);
#pragma unroll
                for (int t = 0; t < 4; ++t) {
                    MFMA16(P[t], ah, wh[t][q]);
                    MFMA16(Q[t], al, wh[t][q]);
                    if (q & 1) { MFMA16(P[t], ah, wl[t][q]); }
                    else       { MFMA16(Q[t], ah, wl[t][q]); }
                }
            }
#pragma unroll
            for (int r = 0; r < 4; ++r) {
                float mi = nb[0] - P[0][r] - Q[0][r];
                float mf = nb[1] - P[1][r] - Q[1][r];
                float mg = nb[2] - P[2][r] - Q[2][r];
                float mo = nb[3] - P[3][r] - Q[3][r];
                float hn = activ(mi, mf, mg, mo, cr[r]);
                unsigned short hi = f2bf_rne(hn);
                float res = hn - __uint_as_float((unsigned)hi << 16);
                unsigned short lo = f2bf_rne(res);
                *(unsigned short*)(hbn + wo[r]) = hi;
                *(unsigned short*)(lbn + wo[r]) = lo;
            }
        };

        float4 xa0, xa1, xb0, xb1;
        xload(xa0, xa1, 0);
        for (int t = 0; t < 256; t += 2) {
            if (t > 0) {
                exp0(t, 0);
                if ((t & 3) == 0) {
                    vm_drain();
                    __syncthreads();
                    if (tid == 0) astu(&ctr0[p * 16], (unsigned)t);
                }
            }
            xload(xb0, xb1, t + 1);
            step0(t, 0, xa0, xa1);
            lds_barrier();
            exp0(t + 1, 1);
            xload(xa0, xa1, t + 2 > 255 ? 255 : t + 2);
            step0(t + 1, 1, xb0, xb1);
            lds_barrier();
        }
        exp0(256, 0);                      // h_255
        vm_drain();
        __syncthreads();
        if (tid == 0) astu(&ctr0[p * 16], 256u);
        return;
    }

    // ================= role1: layer1 recurrence + fc head ================
    {
        auto pxg = [&](float (&d)[4][4], int u) __attribute__((always_inline)) {
            int slot = (u >> 2) & (RING - 1);
            int tt   = u & 3;
            const float* b = xgr + (((size_t)slot * 32 + p) * WIN + tt) * 8192
                                 + j * 16 + quad * 4;
#pragma unroll
            for (int tg = 0; tg < 4; ++tg) {
                unsigned long long a0 = ald64((const unsigned long long*)(b + tg * 2048));
                unsigned long long a1 = ald64((const unsigned long long*)(b + tg * 2048 + 2));
                d[tg][0] = __uint_as_float((unsigned)a0);
                d[tg][1] = __uint_as_float((unsigned)(a0 >> 32));
                d[tg][2] = __uint_as_float((unsigned)a1);
                d[tg][3] = __uint_as_float((unsigned)(a1 >> 32));
            }
        };

        auto step1 = [&](int TL, int BUF, const float (&xgv)[4][4])
            __attribute__((always_inline)) {
            const char* hb = (const char*)&HA[BUF][0][0];
            const char* lb = (const char*)&HL[BUF][0][0];
            char* hbn = (char*)&HA[BUF ^ 1][0][0];
            char* lbn = (char*)&HL[BUF ^ 1][0][0];
            f32x4 P[4] = {}, Q[4] = {};
#pragma unroll
            for (int q = 0; q < 4; ++q) {
                bf16x8 ah = *(const bf16x8*)(hb + ro[q]);
                bf16x8 al = *(const bf16x8*)(lb + ro[q]);
#pragma unroll
                for (int t = 0; t < 4; ++t) {
                    MFMA16(P[t], ah, wh[t][q]);
                    MFMA16(Q[t], al, wh[t][q]);
                    if (q & 1) { MFMA16(P[t], ah, wl[t][q]); }
                    else       { MFMA16(Q[t], ah, wl[t][q]); }
                }
            }
#pragma unroll
            for (int r = 0; r < 4; ++r) {
                float mi = xgv[0][r] - P[0][r] - Q[0][r];
                float mf = xgv[1][r] - P[1][r] - Q[1][r];
                float mg = xgv[2][r] - P[2][r] - Q[2][r];
                float mo = xgv[3][r] - P[3][r] - Q[3][r];
                float hn = activ(mi, mf, mg, mo, cr[r]);
                unsigned short hi = f2bf_rne(hn);
                float res = hn - __uint_as_float((unsigned)hi << 16);
                unsigned short lo = f2bf_rne(res);
                *(unsigned short*)(hbn + wo[r]) = hi;
                *(unsigned short*)(lbn + wo[r]) = lo;
                if (TL == 255)
                    h1s[(size_t)(p * 16 + quad * 4 + r) * NH + j] = hn;
            }
        };

        // prologue: first window
        while (aldu(&flagW[p * 64 + 0]) == 0) __builtin_amdgcn_s_sleep(8);
        asm volatile("" ::: "memory");
        float xga[4][4], xgb[4][4];
        pxg(xga, 0);

        for (int u = 0; u < 256; u += 2) {
            if ((u & 3) == 0 && u > 0) {
                if (tid == 0) astu(&ctr1[p * 16], (unsigned)(u >> 2));
            }
            if ((u & 3) == 2 && (u >> 2) < NWIN - 1) {
                int wn = (u >> 2) + 1;
                while (aldu(&flagW[p * 64 + wn]) == 0) __builtin_amdgcn_s_sleep(8);
                asm volatile("" ::: "memory");
            }
            pxg(xgb, u + 1 > 255 ? 255 : u + 1);
            step1(u, 0, xga);
            lds_barrier();
            pxg(xga, u + 2 > 255 ? 255 : u + 2);
            step1(u + 1, 1, xgb);
            lds_barrier();
        }

        // fc head: out[b] = fc2 . relu(fc1 @ h1_last + b1) + b2
        vm_drain();
        __syncthreads();
        const int g = tid >> 5;
        const int l = tid & 31;
        const float4* h4 = (const float4*)(h1s + (size_t)(p * 16 + g) * NH);
        const float4* w0 = (const float4*)(fc1w + (size_t)l * NH);
        const float4* w1 = (const float4*)(fc1w + (size_t)(l + 32) * NH);
        float a0 = fc1b[l], a1 = fc1b[l + 32];
#pragma unroll
        for (int q = 0; q < 32; ++q) {
            float4 h = h4[q], u = w0[q], v = w1[q];
            a0 += u.x * h.x + u.y * h.y + u.z * h.z + u.w * h.w;
            a1 += v.x * h.x + v.y * h.y + v.z * h.z + v.w * h.w;
        }
        float pv = fc2w[l] * fmaxf(a0, 0.f) + fc2w[l + 32] * fmaxf(a1, 0.f);
#pragma unroll
        for (int off = 16; off > 0; off >>= 1) pv += __shfl_down(pv, off, 32);
        if (l == 0) out[p * 16 + g] = pv + fc2b[0];
    }
}

extern "C" void kernel_launch(void* const* d_in, const int* in_sizes, int n_in,
                              void* d_out, int out_size, void* d_ws, size_t ws_size,
                              hipStream_t stream)
{
    const float* x     = (const float*)d_in[0];
    const float* w_ih0 = (const float*)d_in[1];
    const float* w_hh0 = (const float*)d_in[2];
    const float* b_ih0 = (const float*)d_in[3];
    const float* b_hh0 = (const float*)d_in[4];
    const float* w_ih1 = (const float*)d_in[5];
    const float* w_hh1 = (const float*)d_in[6];
    const float* b_ih1 = (const float*)d_in[7];
    const float* b_hh1 = (const float*)d_in[8];
    const float* fc1w  = (const float*)d_in[9];
    const float* fc1b  = (const float*)d_in[10];
    const float* fc2w  = (const float*)d_in[11];
    const float* fc2b  = (const float*)d_in[12];
    float* out = (float*)d_out;
    float* ws  = (float*)d_ws;

    // ws layout (floats):
    //  h0 planes: 256 t x 2 pl x 32 p x 4KB  = 16.78M floats (64 MB)
    //  xg ring  : RING x 32 p x WIN x 8192   = 16.78M floats (64 MB)
    //  h1s 64K | flags 3072 u32  -> total ~134.5 MB (<= proven 152 MB ws)
    size_t o_h0  = 0;
    size_t o_xgr = o_h0 + (size_t)256 * 2 * 32 * 1024;   // u64 count*2 floats
    size_t o_h1s = o_xgr + (size_t)RING * 32 * WIN * 8192;
    size_t o_flg = o_h1s + (size_t)NB * NH;

    unsigned long long* h0pl = (unsigned long long*)(ws + o_h0);
    float*    xgr   = ws + o_xgr;
    float*    h1sp  = ws + o_h1s;
    unsigned* ctr0  = (unsigned*)(ws + o_flg);
    unsigned* flagW = ctr0 + 32 * 16;
    unsigned* ctr1  = flagW + 32 * 64;

    hipMemsetAsync(ctr0, 0, (32 * 16 + 32 * 64 + 32 * 16) * sizeof(unsigned),
                   stream);

    void* args[] = {
        (void*)&x,
        (void*)&w_hh0, (void*)&w_hh1,
        (void*)&w_ih0, (void*)&b_ih0, (void*)&b_hh0,
        (void*)&w_ih1, (void*)&b_ih1, (void*)&b_hh1,
        (void*)&fc1w, (void*)&fc1b, (void*)&fc2w, (void*)&fc2b,
        (void*)&h0pl, (void*)&xgr, (void*)&h1sp, (void*)&out,
        (void*)&ctr0, (void*)&flagW, (void*)&ctr1,
    };
    hipLaunchCooperativeKernel((const void*)fused, dim3(256), dim3(512),
                               args, 0, stream);
}